// Round 2
// baseline (5901.392 us; speedup 1.0000x reference)
//
#include <hip/hip_runtime.h>
#include <math.h>
#include <float.h>

#define NFEAT 256
#define DIMH 16
#define KTOP 40

// ---------------------------------------------------------------- degree
__global__ void deg_kernel(const int* __restrict__ dst, int* __restrict__ deg, int E) {
    int e = blockIdx.x * blockDim.x + threadIdx.x;
    if (e < E) atomicAdd(&deg[dst[e]], 1);
}

__global__ void dinv_kernel(const int* __restrict__ deg, float* __restrict__ dinv, int N) {
    int i = blockIdx.x * blockDim.x + threadIdx.x;
    if (i < N) dinv[i] = rsqrtf((float)(deg[i] + 1));   // +1 self-loop
}

// ---------------------------------------------------------------- x @ W1  (256 -> 16)
// 16 rows per block, x rows + W1 staged in LDS.
__global__ __launch_bounds__(256) void xw1_kernel(const float* __restrict__ x,
                                                  const float* __restrict__ W1,
                                                  float* __restrict__ t, int N) {
    __shared__ float xs[16][NFEAT + 1];
    __shared__ float wl[NFEAT][DIMH];
    const int tid = threadIdx.x;
    const int r0 = blockIdx.x * 16;

    #pragma unroll
    for (int j = 0; j < 16; ++j) {                 // 4096 = 256*16 W1 elements
        int idx = j * 256 + tid;
        wl[idx >> 4][idx & 15] = W1[idx];
    }
    #pragma unroll
    for (int j = 0; j < 16; ++j) {                 // 16 rows x 256 feats
        int row = j, col = tid;
        int r = r0 + row;
        xs[row][col] = (r < N) ? x[(size_t)r * NFEAT + col] : 0.f;
    }
    __syncthreads();

    const int row = tid >> 4, o = tid & 15;
    float acc = 0.f;
    #pragma unroll 8
    for (int c = 0; c < NFEAT; ++c)
        acc += xs[row][c] * wl[c][o];
    int r = r0 + row;
    if (r < N) t[(size_t)r * DIMH + o] = acc;
}

// ---------------------------------------------------------------- agg init: self-loop term
__global__ void init_agg_kernel(const float* __restrict__ t, const float* __restrict__ dinv,
                                float* __restrict__ agg, int N) {
    int i = blockIdx.x * blockDim.x + threadIdx.x;
    if (i >= N) return;
    float w = dinv[i] * dinv[i];
    const float4* tv = (const float4*)(t + (size_t)i * DIMH);
    float4* av = (float4*)(agg + (size_t)i * DIMH);
    #pragma unroll
    for (int q = 0; q < 4; ++q) {
        float4 v = tv[q];
        v.x *= w; v.y *= w; v.z *= w; v.w *= w;
        av[q] = v;
    }
}

// ---------------------------------------------------------------- edge scatter (atomics)
__global__ void scatter_kernel(const int* __restrict__ src, const int* __restrict__ dst,
                               const float* __restrict__ dinv, const float* __restrict__ t,
                               float* __restrict__ agg, int E) {
    int e = blockIdx.x * blockDim.x + threadIdx.x;
    if (e >= E) return;
    int s = src[e], d = dst[e];
    float w = dinv[s] * dinv[d];
    const float4* tv = (const float4*)(t + (size_t)s * DIMH);
    float* ap = agg + (size_t)d * DIMH;
    #pragma unroll
    for (int q = 0; q < 4; ++q) {
        float4 v = tv[q];
        atomicAdd(ap + 4 * q + 0, w * v.x);
        atomicAdd(ap + 4 * q + 1, w * v.y);
        atomicAdd(ap + 4 * q + 2, w * v.z);
        atomicAdd(ap + 4 * q + 3, w * v.w);
    }
}

// ---------------------------------------------------------------- relu(agg+b1) @ W2  (16 -> 16)
__global__ __launch_bounds__(256) void hw2_kernel(const float* __restrict__ agg,
                                                  const float* __restrict__ b1,
                                                  const float* __restrict__ W2,
                                                  float* __restrict__ t2, int N) {
    __shared__ float wl[DIMH * DIMH];
    __shared__ float bl[DIMH];
    int tid = threadIdx.x;
    wl[tid & 255] = W2[tid & 255];
    if (tid < DIMH) bl[tid] = b1[tid];
    __syncthreads();

    int i = blockIdx.x * blockDim.x + tid;
    if (i >= N) return;
    float h[DIMH];
    const float4* av = (const float4*)(agg + (size_t)i * DIMH);
    #pragma unroll
    for (int q = 0; q < 4; ++q) {
        float4 v = av[q];
        h[4 * q + 0] = fmaxf(v.x + bl[4 * q + 0], 0.f);
        h[4 * q + 1] = fmaxf(v.y + bl[4 * q + 1], 0.f);
        h[4 * q + 2] = fmaxf(v.z + bl[4 * q + 2], 0.f);
        h[4 * q + 3] = fmaxf(v.w + bl[4 * q + 3], 0.f);
    }
    float out[DIMH];
    #pragma unroll
    for (int o = 0; o < DIMH; ++o) {
        float acc = 0.f;
        #pragma unroll
        for (int c = 0; c < DIMH; ++c) acc += h[c] * wl[c * DIMH + o];
        out[o] = acc;
    }
    float4* ov = (float4*)(t2 + (size_t)i * DIMH);
    #pragma unroll
    for (int q = 0; q < 4; ++q)
        ov[q] = make_float4(out[4 * q], out[4 * q + 1], out[4 * q + 2], out[4 * q + 3]);
}

// ---------------------------------------------------------------- relu(agg+b2) -> h2
__global__ void relu_kernel(const float* __restrict__ agg, const float* __restrict__ b,
                            float* __restrict__ h, int NT) {
    int i = blockIdx.x * blockDim.x + threadIdx.x;
    if (i < NT) h[i] = fmaxf(agg[i] + b[i & (DIMH - 1)], 0.f);
}

// ---------------------------------------------------------------- sort-pool + fc (one block/graph)
__global__ __launch_bounds__(256) void pool_kernel(const float* __restrict__ h,
                                                   const int* __restrict__ batch,
                                                   const float* __restrict__ fc_w,
                                                   const float* __restrict__ fc_b,
                                                   float* __restrict__ out, int N) {
    __shared__ float svals[2048];
    __shared__ float rval[256];
    __shared__ int   rpos[256];
    __shared__ int   sel_s;
    const int g = blockIdx.x;
    const int tid = threadIdx.x;

    // lower_bound(batch, g) and lower_bound(batch, g+1)
    int lo = 0, hi = N;
    while (lo < hi) { int mid = (lo + hi) >> 1; if (batch[mid] < g) lo = mid + 1; else hi = mid; }
    const int start = lo;
    lo = start; hi = N;
    while (lo < hi) { int mid = (lo + hi) >> 1; if (batch[mid] < g + 1) lo = mid + 1; else hi = mid; }
    int cnt = lo - start;
    if (cnt > 2048) cnt = 2048;   // cannot occur for this distribution (mean 390, sd ~20)

    for (int i = tid; i < cnt; i += 256)
        svals[i] = h[(size_t)(start + i) * DIMH + (DIMH - 1)];
    __syncthreads();

    float acc = 0.f;
    const int kk = cnt < KTOP ? cnt : KTOP;
    for (int j = 0; j < kk; ++j) {
        // block argmax with (val desc, idx asc) ordering — stable-sort tie-break
        float bv = -FLT_MAX; int bp = 0x7fffffff;
        for (int i = tid; i < cnt; i += 256) {
            float v = svals[i];
            if (v > bv || (v == bv && i < bp)) { bv = v; bp = i; }
        }
        rval[tid] = bv; rpos[tid] = bp;
        __syncthreads();
        #pragma unroll
        for (int sft = 128; sft > 0; sft >>= 1) {
            if (tid < sft) {
                float ov = rval[tid + sft]; int op = rpos[tid + sft];
                if (ov > rval[tid] || (ov == rval[tid] && op < rpos[tid])) {
                    rval[tid] = ov; rpos[tid] = op;
                }
            }
            __syncthreads();
        }
        if (tid == 0) { sel_s = rpos[0]; svals[rpos[0]] = -FLT_MAX; }
        __syncthreads();
        int n = start + sel_s;
        if (tid < DIMH) acc += h[(size_t)n * DIMH + tid] * fc_w[j * DIMH + tid];
        __syncthreads();
    }

    rval[tid] = acc;
    __syncthreads();
    if (tid == 0) {
        float s = 0.f;
        #pragma unroll
        for (int c = 0; c < DIMH; ++c) s += rval[c];
        out[g] = s + fc_b[0];
    }
}

// ----------------------------------------------------------------
extern "C" void kernel_launch(void* const* d_in, const int* in_sizes, int n_in,
                              void* d_out, int out_size, void* d_ws, size_t ws_size,
                              hipStream_t stream) {
    const float* x    = (const float*)d_in[0];
    const int*   ei   = (const int*)d_in[1];
    const int*   batch= (const int*)d_in[2];
    // d_in[3] = edge_weight: ignored by reference forward
    const float* W1   = (const float*)d_in[4];
    const float* b1   = (const float*)d_in[5];
    const float* W2   = (const float*)d_in[6];
    const float* b2   = (const float*)d_in[7];
    const float* fc_w = (const float*)d_in[8];
    const float* fc_b = (const float*)d_in[9];
    float* out = (float*)d_out;

    const int N = in_sizes[2];            // 200000
    const int E = in_sizes[1] / 2;        // 3200000
    const int G = out_size;               // 512
    const int* src = ei;
    const int* dst = ei + E;

    char* ws = (char*)d_ws;
    int*   deg    = (int*)ws;                              // N*4      < 1 MB
    float* dinv   = (float*)(ws + (1u << 20));             // N*4      < 1 MB
    float* tbuf   = (float*)(ws + (2u << 20));             // N*16*4 = 12.8 MB
    float* aggbuf = (float*)(ws + (16u << 20));            // 12.8 MB ; total 28.8 MB

    const int TB = 256;
    const int gE = (E + TB - 1) / TB;
    const int gN = (N + TB - 1) / TB;

    hipMemsetAsync(deg, 0, (size_t)N * sizeof(int), stream);
    deg_kernel<<<gE, TB, 0, stream>>>(dst, deg, E);
    dinv_kernel<<<gN, TB, 0, stream>>>(deg, dinv, N);

    // layer 1: t1 = x@W1 ; agg = D^-1 self + edges ; (bias+relu fused into hw2)
    xw1_kernel<<<(N + 15) / 16, TB, 0, stream>>>(x, W1, tbuf, N);
    init_agg_kernel<<<gN, TB, 0, stream>>>(tbuf, dinv, aggbuf, N);
    scatter_kernel<<<gE, TB, 0, stream>>>(src, dst, dinv, tbuf, aggbuf, E);

    // layer 2: t2 = relu(agg+b1)@W2 (tbuf reused) ; aggregate again
    hw2_kernel<<<gN, TB, 0, stream>>>(aggbuf, b1, W2, tbuf, N);
    init_agg_kernel<<<gN, TB, 0, stream>>>(tbuf, dinv, aggbuf, N);
    scatter_kernel<<<gE, TB, 0, stream>>>(src, dst, dinv, tbuf, aggbuf, E);

    // h2 = relu(agg+b2) (tbuf reused as h2)
    relu_kernel<<<(N * DIMH + TB - 1) / TB, TB, 0, stream>>>(aggbuf, b2, tbuf, N * DIMH);

    // sort-pool + fc
    pool_kernel<<<G, TB, 0, stream>>>(tbuf, batch, fc_w, fc_b, out, N);
}

// Round 3
// 941.968 us; speedup vs baseline: 6.2650x; 6.2650x over previous
//
#include <hip/hip_runtime.h>
#include <math.h>
#include <float.h>

#define NFEAT 256
#define DIMH 16
#define KTOP 40
#define SC 1024   // scan chunk (elements per block); requires N <= 256*1024

// ---------------------------------------------------------------- degree
__global__ void deg_kernel(const int* __restrict__ dst, int* __restrict__ deg, int E) {
    int e = blockIdx.x * blockDim.x + threadIdx.x;
    if (e < E) atomicAdd(&deg[dst[e]], 1);
}

__global__ void dinv_kernel(const int* __restrict__ deg, float* __restrict__ dinv, int N) {
    int i = blockIdx.x * blockDim.x + threadIdx.x;
    if (i < N) dinv[i] = rsqrtf((float)(deg[i] + 1));   // +1 self-loop
}

// ---------------------------------------------------------------- exclusive scan (3 kernels)
__global__ __launch_bounds__(256) void scan1_kernel(const int* __restrict__ deg,
                                                    int* __restrict__ bsum, int N) {
    __shared__ int s[256];
    const int b = blockIdx.x, tid = threadIdx.x;
    const int base = b * SC + tid * 4;
    int v = 0;
    #pragma unroll
    for (int q = 0; q < 4; ++q) { int i = base + q; if (i < N) v += deg[i]; }
    s[tid] = v; __syncthreads();
    #pragma unroll
    for (int sft = 128; sft > 0; sft >>= 1) {
        if (tid < sft) s[tid] += s[tid + sft];
        __syncthreads();
    }
    if (tid == 0) bsum[b] = s[0];
}

__global__ __launch_bounds__(256) void scan2_kernel(const int* __restrict__ bsum,
                                                    int* __restrict__ boff, int nb) {
    __shared__ int s[256];
    const int tid = threadIdx.x;
    int v = (tid < nb) ? bsum[tid] : 0;
    s[tid] = v; __syncthreads();
    #pragma unroll
    for (int d = 1; d < 256; d <<= 1) {   // inclusive Hillis-Steele
        int add = (tid >= d) ? s[tid - d] : 0;
        __syncthreads();
        s[tid] += add;
        __syncthreads();
    }
    boff[tid] = s[tid] - v;               // exclusive
}

__global__ __launch_bounds__(256) void scan3_kernel(const int* __restrict__ deg,
                                                    const int* __restrict__ boff,
                                                    int* __restrict__ row_start,
                                                    int* __restrict__ cursor, int N, int E) {
    __shared__ int s[256];
    const int b = blockIdx.x, tid = threadIdx.x;
    const int base = b * SC + tid * 4;
    int v[4]; int sum = 0;
    #pragma unroll
    for (int q = 0; q < 4; ++q) { int i = base + q; v[q] = (i < N) ? deg[i] : 0; sum += v[q]; }
    s[tid] = sum; __syncthreads();
    #pragma unroll
    for (int d = 1; d < 256; d <<= 1) {   // inclusive scan of thread sums
        int add = (tid >= d) ? s[tid - d] : 0;
        __syncthreads();
        s[tid] += add;
        __syncthreads();
    }
    int run = boff[b] + (s[tid] - sum);   // exclusive offset of this thread's chunk
    #pragma unroll
    for (int q = 0; q < 4; ++q) {
        int i = base + q;
        if (i < N) { row_start[i] = run; cursor[i] = run; }
        run += v[q];
    }
    if (b == 0 && tid == 0) row_start[N] = E;   // total degree == E
}

// ---------------------------------------------------------------- CSR fill: (src, w) packed 8B
__global__ void fill_kernel(const int* __restrict__ src, const int* __restrict__ dst,
                            const float* __restrict__ dinv, int* __restrict__ cursor,
                            int2* __restrict__ csr, int E) {
    int e = blockIdx.x * blockDim.x + threadIdx.x;
    if (e >= E) return;
    int s = src[e], d = dst[e];
    int pos = atomicAdd(&cursor[d], 1);
    csr[pos] = make_int2(s, __float_as_int(dinv[s] * dinv[d]));
}

// ---------------------------------------------------------------- x @ W1  (256 -> 16)
__global__ __launch_bounds__(256) void xw1_kernel(const float* __restrict__ x,
                                                  const float* __restrict__ W1,
                                                  float* __restrict__ t, int N) {
    __shared__ float xs[16][NFEAT + 1];
    __shared__ float wl[NFEAT][DIMH];
    const int tid = threadIdx.x;
    const int r0 = blockIdx.x * 16;

    #pragma unroll
    for (int j = 0; j < 16; ++j) {
        int idx = j * 256 + tid;
        wl[idx >> 4][idx & 15] = W1[idx];
    }
    #pragma unroll
    for (int j = 0; j < 16; ++j) {
        int r = r0 + j;
        xs[j][tid] = (r < N) ? x[(size_t)r * NFEAT + tid] : 0.f;
    }
    __syncthreads();

    const int row = tid >> 4, o = tid & 15;
    float acc = 0.f;
    #pragma unroll 8
    for (int c = 0; c < NFEAT; ++c)
        acc += xs[row][c] * wl[c][o];
    int r = r0 + row;
    if (r < N) t[(size_t)r * DIMH + o] = acc;
}

// ---------------------------------------------------------------- CSR gather + bias + relu
// 16 lanes per dst node (lane = channel); neighbor row read = one coalesced 64B transaction.
__global__ __launch_bounds__(256) void gather_kernel(const float* __restrict__ t,
                                                     const float* __restrict__ dinv,
                                                     const int* __restrict__ row_start,
                                                     const int2* __restrict__ csr,
                                                     const float* __restrict__ bias,
                                                     float* __restrict__ out, int N) {
    const int tid = threadIdx.x;
    const int lane = tid & 15;                 // channel
    const int node = blockIdx.x * 16 + (tid >> 4);
    if (node >= N) return;

    float di = dinv[node];
    float acc = di * di * t[(size_t)node * DIMH + lane];   // self-loop
    int j = row_start[node];
    const int e = row_start[node + 1];
    for (; j + 1 < e; j += 2) {                // 2-deep for load pipelining
        int2 e0 = csr[j], e1 = csr[j + 1];
        float v0 = t[(size_t)e0.x * DIMH + lane];
        float v1 = t[(size_t)e1.x * DIMH + lane];
        acc += __int_as_float(e0.y) * v0;
        acc += __int_as_float(e1.y) * v1;
    }
    if (j < e) {
        int2 e0 = csr[j];
        acc += __int_as_float(e0.y) * t[(size_t)e0.x * DIMH + lane];
    }
    out[(size_t)node * DIMH + lane] = fmaxf(acc + bias[lane], 0.f);
}

// ---------------------------------------------------------------- t2 = h1 @ W2  (16 -> 16)
__global__ __launch_bounds__(256) void mm2_kernel(const float* __restrict__ h1,
                                                  const float* __restrict__ W2,
                                                  float* __restrict__ t2, int N) {
    __shared__ float wl[DIMH * DIMH];
    int tid = threadIdx.x;
    wl[tid] = W2[tid];   // blockDim 256 == DIMH*DIMH
    __syncthreads();

    int i = blockIdx.x * blockDim.x + tid;
    if (i >= N) return;
    float h[DIMH];
    const float4* av = (const float4*)(h1 + (size_t)i * DIMH);
    #pragma unroll
    for (int q = 0; q < 4; ++q) {
        float4 v = av[q];
        h[4 * q + 0] = v.x; h[4 * q + 1] = v.y; h[4 * q + 2] = v.z; h[4 * q + 3] = v.w;
    }
    float out[DIMH];
    #pragma unroll
    for (int o = 0; o < DIMH; ++o) {
        float acc = 0.f;
        #pragma unroll
        for (int c = 0; c < DIMH; ++c) acc += h[c] * wl[c * DIMH + o];
        out[o] = acc;
    }
    float4* ov = (float4*)(t2 + (size_t)i * DIMH);
    #pragma unroll
    for (int q = 0; q < 4; ++q)
        ov[q] = make_float4(out[4 * q], out[4 * q + 1], out[4 * q + 2], out[4 * q + 3]);
}

// ---------------------------------------------------------------- sort-pool + fc (one block/graph)
__global__ __launch_bounds__(256) void pool_kernel(const float* __restrict__ h,
                                                   const int* __restrict__ batch,
                                                   const float* __restrict__ fc_w,
                                                   const float* __restrict__ fc_b,
                                                   float* __restrict__ out, int N) {
    __shared__ float svals[2048];
    __shared__ float rval[256];
    __shared__ int   rpos[256];
    __shared__ int   sel_s;
    const int g = blockIdx.x;
    const int tid = threadIdx.x;

    int lo = 0, hi = N;
    while (lo < hi) { int mid = (lo + hi) >> 1; if (batch[mid] < g) lo = mid + 1; else hi = mid; }
    const int start = lo;
    lo = start; hi = N;
    while (lo < hi) { int mid = (lo + hi) >> 1; if (batch[mid] < g + 1) lo = mid + 1; else hi = mid; }
    int cnt = lo - start;
    if (cnt > 2048) cnt = 2048;

    for (int i = tid; i < cnt; i += 256)
        svals[i] = h[(size_t)(start + i) * DIMH + (DIMH - 1)];
    __syncthreads();

    float acc = 0.f;
    const int kk = cnt < KTOP ? cnt : KTOP;
    for (int j = 0; j < kk; ++j) {
        float bv = -FLT_MAX; int bp = 0x7fffffff;
        for (int i = tid; i < cnt; i += 256) {
            float v = svals[i];
            if (v > bv || (v == bv && i < bp)) { bv = v; bp = i; }
        }
        rval[tid] = bv; rpos[tid] = bp;
        __syncthreads();
        #pragma unroll
        for (int sft = 128; sft > 0; sft >>= 1) {
            if (tid < sft) {
                float ov = rval[tid + sft]; int op = rpos[tid + sft];
                if (ov > rval[tid] || (ov == rval[tid] && op < rpos[tid])) {
                    rval[tid] = ov; rpos[tid] = op;
                }
            }
            __syncthreads();
        }
        if (tid == 0) { sel_s = rpos[0]; svals[rpos[0]] = -FLT_MAX; }
        __syncthreads();
        int n = start + sel_s;
        if (tid < DIMH) acc += h[(size_t)n * DIMH + tid] * fc_w[j * DIMH + tid];
        __syncthreads();
    }

    rval[tid] = acc;
    __syncthreads();
    if (tid == 0) {
        float s = 0.f;
        #pragma unroll
        for (int c = 0; c < DIMH; ++c) s += rval[c];
        out[g] = s + fc_b[0];
    }
}

// ----------------------------------------------------------------
extern "C" void kernel_launch(void* const* d_in, const int* in_sizes, int n_in,
                              void* d_out, int out_size, void* d_ws, size_t ws_size,
                              hipStream_t stream) {
    const float* x    = (const float*)d_in[0];
    const int*   ei   = (const int*)d_in[1];
    const int*   batch= (const int*)d_in[2];
    // d_in[3] = edge_weight: ignored by reference forward
    const float* W1   = (const float*)d_in[4];
    const float* b1   = (const float*)d_in[5];
    const float* W2   = (const float*)d_in[6];
    const float* b2   = (const float*)d_in[7];
    const float* fc_w = (const float*)d_in[8];
    const float* fc_b = (const float*)d_in[9];
    float* out = (float*)d_out;

    const int N = in_sizes[2];            // 200000
    const int E = in_sizes[1] / 2;        // 3200000
    const int G = out_size;               // 512
    const int* src = ei;
    const int* dst = ei + E;

    char* ws = (char*)d_ws;
    const size_t MB = 1u << 20;
    int*   deg       = (int*)(ws + 0 * MB);       // N*4
    float* dinv      = (float*)(ws + 1 * MB);     // N*4
    int*   row_start = (int*)(ws + 2 * MB);       // (N+1)*4
    int*   cursor    = (int*)(ws + 3 * MB);       // N*4
    int*   bsum      = (int*)(ws + 4 * MB);       // <=256 ints
    int*   boff      = (int*)(ws + 4 * MB + 4096);
    float* tbuf      = (float*)(ws + 5 * MB);     // N*16*4 = 12.8 MB
    float* hbuf      = (float*)(ws + 18 * MB);    // 12.8 MB
    int2*  csr       = (int2*)(ws + 31 * MB);     // E*8 = 25.6 MB  (total ~57 MB)

    const int TB = 256;
    const int gE = (E + TB - 1) / TB;
    const int gN = (N + TB - 1) / TB;
    const int nScan = (N + SC - 1) / SC;          // 196 <= 256

    // graph structure: degree -> dinv -> CSR (counting sort by dst)
    hipMemsetAsync(deg, 0, (size_t)N * sizeof(int), stream);
    deg_kernel<<<gE, TB, 0, stream>>>(dst, deg, E);
    dinv_kernel<<<gN, TB, 0, stream>>>(deg, dinv, N);
    scan1_kernel<<<nScan, TB, 0, stream>>>(deg, bsum, N);
    scan2_kernel<<<1, TB, 0, stream>>>(bsum, boff, nScan);
    scan3_kernel<<<nScan, TB, 0, stream>>>(deg, boff, row_start, cursor, N, E);
    fill_kernel<<<gE, TB, 0, stream>>>(src, dst, dinv, cursor, csr, E);

    // layer 1: t1 = x@W1 ; h1 = relu(gather(t1) + b1)
    xw1_kernel<<<(N + 15) / 16, TB, 0, stream>>>(x, W1, tbuf, N);
    gather_kernel<<<(N + 15) / 16, TB, 0, stream>>>(tbuf, dinv, row_start, csr, b1, hbuf, N);

    // layer 2: t2 = h1@W2 ; h2 = relu(gather(t2) + b2)
    mm2_kernel<<<gN, TB, 0, stream>>>(hbuf, W2, tbuf, N);
    gather_kernel<<<(N + 15) / 16, TB, 0, stream>>>(tbuf, dinv, row_start, csr, b2, hbuf, N);

    // sort-pool + fc
    pool_kernel<<<G, TB, 0, stream>>>(hbuf, batch, fc_w, fc_b, out, N);
}